// Round 19
// baseline (55.795 us; speedup 1.0000x reference)
//
#include <hip/hip_runtime.h>
#include <hip/hip_bf16.h>

// Problem constants: B=2, C=64, H=64, W=64 -> N=8192 tokens, DH=32.
#define N_TOK   8192
#define DH      32
#define CCH     64
#define HWSZ    4096
#define LOG2E   1.4426950408889634f
#define NCH_Z   32     // i-chunks in pass A (ilen = 256)
#define NCH_O   16     // j-chunks in pass B (jlen = 512, two staged halves)
#define KROW    40     // padded LDS row stride (shorts): 80B -> b128 conflict-free
#define VROW    264    // padded VT row stride (shorts) — R13-proven

typedef __attribute__((ext_vector_type(8))) short  bf16x8;
typedef __attribute__((ext_vector_type(4))) short  bf16x4;
typedef __attribute__((ext_vector_type(4))) float  f32x4;

// Bit-pattern f32 -> bf16 short (MFMA operand vectors / LDS shorts ONLY —
// never assign the result to a __hip_bfloat16: that would value-convert).
static __device__ __forceinline__ short f2bf(float f) {
    __hip_bfloat16 h = __float2bfloat16(f);
    return __builtin_bit_cast(short, h);
}
static __device__ __forceinline__ float bf2f(short s) {
    unsigned u = ((unsigned)(unsigned short)s) << 16;
    return __builtin_bit_cast(float, u);
}

// A/B fragment for mfma_f32_16x16x32_bf16 from row-major [rows][32] bf16 in
// GLOBAL memory: lane l supplies row row0+(l&15), k = 8*(l>>4)..+8.
static __device__ __forceinline__ bf16x8 load_frag8(const __hip_bfloat16* __restrict__ base,
                                                    int row0, int l) {
    const __hip_bfloat16* p = base + (size_t)(row0 + (l & 15)) * DH + ((l >> 4) << 3);
    return *reinterpret_cast<const bf16x8*>(p);
}

// ---------------------------------------------------------------------------
// K1: q/k/v projections (1024 blocks, 8 tokens each — measured ~5.7us true).
// Qb pre-scaled by log2e; VTb transposed via LDS. R13 verbatim.
// ---------------------------------------------------------------------------
__global__ __launch_bounds__(256) void k_qkv(
        const float* __restrict__ x,
        const float* __restrict__ w1, const float* __restrict__ b1,
        const float* __restrict__ w2, const float* __restrict__ b2,
        const float* __restrict__ w3, const float* __restrict__ b3,
        __hip_bfloat16* __restrict__ Qb, __hip_bfloat16* __restrict__ Kb,
        __hip_bfloat16* __restrict__ VTb) {
    __shared__ float4 w1s[16][32];
    __shared__ float4 w2s[16][32];
    __shared__ float4 w3s[16][32];
    __shared__ short  vt[32][8];
    int t = threadIdx.x;
    for (int i = t; i < 512; i += 256) {
        int cg = i >> 5, d = i & 31;
        w1s[cg][d] = *reinterpret_cast<const float4*>(w1 + d * CCH + cg * 4);
        w2s[cg][d] = *reinterpret_cast<const float4*>(w2 + d * CCH + cg * 4);
        w3s[cg][d] = *reinterpret_cast<const float4*>(w3 + d * CCH + cg * 4);
    }
    __syncthreads();
    int d = t & 31, nr = t >> 5;
    int n0 = blockIdx.x * 8;
    int n = n0 + nr;
    int b = n >> 12, hw = n & 4095;
    const float* xp = x + (size_t)b * (CCH * HWSZ) + hw;
    float aq = b1[d], ak = b2[d], av = b3[d];
    #pragma unroll
    for (int cg = 0; cg < 16; ++cg) {
        float x0 = xp[(cg * 4 + 0) * HWSZ];
        float x1 = xp[(cg * 4 + 1) * HWSZ];
        float x2 = xp[(cg * 4 + 2) * HWSZ];
        float x3 = xp[(cg * 4 + 3) * HWSZ];
        float4 a = w1s[cg][d];
        aq = fmaf(a.x, x0, aq); aq = fmaf(a.y, x1, aq);
        aq = fmaf(a.z, x2, aq); aq = fmaf(a.w, x3, aq);
        float4 bb = w2s[cg][d];
        ak = fmaf(bb.x, x0, ak); ak = fmaf(bb.y, x1, ak);
        ak = fmaf(bb.z, x2, ak); ak = fmaf(bb.w, x3, ak);
        float4 cc = w3s[cg][d];
        av = fmaf(cc.x, x0, av); av = fmaf(cc.y, x1, av);
        av = fmaf(cc.z, x2, av); av = fmaf(cc.w, x3, av);
    }
    Qb[(size_t)n * DH + d] = __float2bfloat16(aq * LOG2E);
    Kb[(size_t)n * DH + d] = __float2bfloat16(ak);
    vt[d][nr] = f2bf(av);
    __syncthreads();
    if (t < 32) {
        bf16x8 row = *reinterpret_cast<const bf16x8*>(&vt[t][0]);
        *reinterpret_cast<bf16x8*>(VTb + (size_t)t * N_TOK + n0) = row;
    }
}

// ---------------------------------------------------------------------------
// K2 (pass A): Zp[ic][j] = sum_{i in chunk ic} exp2(q~_i . k_j).
// R13 verbatim: 256-thread block, 4 waves sharing a staged 256-row Q chunk
// ([256][40] padded -> conflict-free b128). Wave w owns j-tile jtg*4+w.
// Grid = 32 ic x 32 jtg = 1024 blocks.
// ---------------------------------------------------------------------------
__global__ __launch_bounds__(256, 4) void k_z(
        const __hip_bfloat16* __restrict__ Qb, const __hip_bfloat16* __restrict__ Kb,
        float* __restrict__ Zp) {
    __shared__ short Qs[256 * KROW];   // 20 KB
    int t = threadIdx.x;
    int ic  = blockIdx.x & 31;           // i-chunk 0..31
    int jtg = blockIdx.x >> 5;           // 0..31
    int i0c = ic * 256;
    #pragma unroll
    for (int p = 0; p < 4; ++p) {
        int row = p * 64 + (t >> 2), seg = t & 3;
        bf16x8 v = *reinterpret_cast<const bf16x8*>(
            Qb + (size_t)(i0c + row) * DH + seg * 8);
        *reinterpret_cast<bf16x8*>(&Qs[row * KROW + seg * 8]) = v;
    }
    __syncthreads();
    int l = t & 63, w = t >> 6;
    int lo16 = l & 15, hi = l >> 4;
    int j0 = (jtg * 4 + w) * 64;
    bf16x8 ka[4];
    #pragma unroll
    for (int f = 0; f < 4; ++f) ka[f] = load_frag8(Kb, j0 + f * 16, l);
    float zac[16];
    #pragma unroll
    for (int k = 0; k < 16; ++k) zac[k] = 0.f;
    const f32x4 z4 = {0.f, 0.f, 0.f, 0.f};
    #pragma unroll 2
    for (int il = 0; il < 256; il += 16) {
        bf16x8 qf = *reinterpret_cast<const bf16x8*>(&Qs[(il + lo16) * KROW + hi * 8]);
        #pragma unroll
        for (int f = 0; f < 4; ++f) {
            f32x4 s = __builtin_amdgcn_mfma_f32_16x16x32_bf16(ka[f], qf, z4, 0, 0, 0);
            #pragma unroll
            for (int r = 0; r < 4; ++r)
                zac[f * 4 + r] += __builtin_amdgcn_exp2f(s[r]);
        }
    }
    #pragma unroll
    for (int k = 0; k < 16; ++k) {
        float z = zac[k];
        z += __shfl_xor(z, 1); z += __shfl_xor(z, 2);
        z += __shfl_xor(z, 4); z += __shfl_xor(z, 8);
        zac[k] = z;
    }
    if ((l & 15) == 0) {
        int jr = (l >> 4) * 4;
        #pragma unroll
        for (int f = 0; f < 4; ++f)
            #pragma unroll
            for (int r = 0; r < 4; ++r)
                Zp[(size_t)ic * N_TOK + j0 + f * 16 + jr + r] = zac[f * 4 + r];
    }
}

// ---------------------------------------------------------------------------
// K3 (pass B): R17 shape (wave owns 64 rows, 4 Q frags, grid 512) + T14
// async-stage split: the h=1 K/V half-tile global loads are ISSUED into
// registers right after the first barrier, so their latency hides under the
// h=0 compute (~5000 cyc); after the next barrier the registers are written
// to LDS with no global stall. Preamble: lrz_j = -log2(Z_j) as QK MFMA C
// operand (R17-proven — e = exp2(s) includes 1/Z).
// ---------------------------------------------------------------------------
__global__ __launch_bounds__(256, 4) void k_af(
        const __hip_bfloat16* __restrict__ Qb, const __hip_bfloat16* __restrict__ Kb,
        const __hip_bfloat16* __restrict__ VTb, const float* __restrict__ Zp,
        __hip_bfloat16* __restrict__ oTp) {
    __shared__ short Ks[256 * KROW];   // 20 KB
    __shared__ short Vs[32 * VROW];    // 16.5 KB
    __shared__ float lrzs[512];        // 2 KB
    int t = threadIdx.x;
    int jc  = blockIdx.x & 15;           // j-chunk (512 cols)
    int itg = blockIdx.x >> 4;           // 0..31
    int j0c = jc * 512;
    {   // lrz = -log2(Z) for 512 cols (fixed order -> deterministic)
        float z0 = 0.f, z1 = 0.f;
        #pragma unroll 8
        for (int c = 0; c < NCH_Z; ++c) {
            z0 += Zp[(size_t)c * N_TOK + j0c + t];
            z1 += Zp[(size_t)c * N_TOK + j0c + 256 + t];
        }
        lrzs[t]       = -__builtin_amdgcn_logf(z0);
        lrzs[t + 256] = -__builtin_amdgcn_logf(z1);
    }
    // staging addresses (R13 pattern)
    int srow = t >> 2, sseg = t & 3;     // K: 4 passes, row p*64+srow, 16B seg
    int vd = t >> 3, vpart = t & 7;      // V: row vd, 32-short part
    const __hip_bfloat16* vsrc0 = VTb + (size_t)vd * N_TOK + j0c + vpart * 32;
    // ---- stage h=0 (load regs -> write LDS) ----
    bf16x8 kr[4], vr[4];
    #pragma unroll
    for (int p = 0; p < 4; ++p)
        kr[p] = *reinterpret_cast<const bf16x8*>(
            Kb + (size_t)(j0c + p * 64 + srow) * DH + sseg * 8);
    #pragma unroll
    for (int q = 0; q < 4; ++q)
        vr[q] = *reinterpret_cast<const bf16x8*>(vsrc0 + q * 8);
    #pragma unroll
    for (int p = 0; p < 4; ++p)
        *reinterpret_cast<bf16x8*>(&Ks[(p * 64 + srow) * KROW + sseg * 8]) = kr[p];
    #pragma unroll
    for (int q = 0; q < 4; ++q)
        *reinterpret_cast<bf16x8*>(&Vs[vd * VROW + vpart * 32 + q * 8]) = vr[q];
    __syncthreads();                      // covers lrzs + h0 tiles
    // ---- T14: ISSUE h=1 loads now; latency hides under h0 compute ----
    #pragma unroll
    for (int p = 0; p < 4; ++p)
        kr[p] = *reinterpret_cast<const bf16x8*>(
            Kb + (size_t)(j0c + 256 + p * 64 + srow) * DH + sseg * 8);
    #pragma unroll
    for (int q = 0; q < 4; ++q)
        vr[q] = *reinterpret_cast<const bf16x8*>(vsrc0 + 256 + q * 8);

    int l = t & 63, w = t >> 6;
    int lo16 = l & 15, hi = l >> 4, hi4 = hi << 2;
    int it = itg * 4 + w;                // 0..127
    int i0 = it * 64;
    bf16x8 qb[4];
    #pragma unroll
    for (int f = 0; f < 4; ++f) qb[f] = load_frag8(Qb, i0 + f * 16, l);
    f32x4 acc0[4], acc1[4];
    #pragma unroll
    for (int f = 0; f < 4; ++f) { acc0[f] = {0.f,0.f,0.f,0.f}; acc1[f] = {0.f,0.f,0.f,0.f}; }
    // ---- compute h=0 ----
    #pragma unroll 2
    for (int jl = 0; jl < 256; jl += 16) {
        f32x4 lz4 = *reinterpret_cast<const f32x4*>(&lrzs[jl + hi4]);
        bf16x8 kaf = *reinterpret_cast<const bf16x8*>(&Ks[(jl + lo16) * KROW + hi * 8]);
        bf16x4 va0 = *reinterpret_cast<const bf16x4*>(&Vs[lo16 * VROW + jl + hi4]);
        bf16x4 va1 = *reinterpret_cast<const bf16x4*>(&Vs[(lo16 + 16) * VROW + jl + hi4]);
        #pragma unroll
        for (int f = 0; f < 4; ++f) {
            f32x4 s = __builtin_amdgcn_mfma_f32_16x16x32_bf16(kaf, qb[f], lz4, 0, 0, 0);
            bf16x4 e;
            #pragma unroll
            for (int r = 0; r < 4; ++r)
                e[r] = f2bf(__builtin_amdgcn_exp2f(s[r]));
            acc0[f] = __builtin_amdgcn_mfma_f32_16x16x16bf16_1k(va0, e, acc0[f], 0, 0, 0);
            acc1[f] = __builtin_amdgcn_mfma_f32_16x16x16bf16_1k(va1, e, acc1[f], 0, 0, 0);
        }
    }
    __syncthreads();                      // all waves done reading h0 LDS
    // ---- write h=1 tiles (registers already resident) ----
    #pragma unroll
    for (int p = 0; p < 4; ++p)
        *reinterpret_cast<bf16x8*>(&Ks[(p * 64 + srow) * KROW + sseg * 8]) = kr[p];
    #pragma unroll
    for (int q = 0; q < 4; ++q)
        *reinterpret_cast<bf16x8*>(&Vs[vd * VROW + vpart * 32 + q * 8]) = vr[q];
    __syncthreads();
    // ---- compute h=1 ----
    #pragma unroll 2
    for (int jl = 0; jl < 256; jl += 16) {
        f32x4 lz4 = *reinterpret_cast<const f32x4*>(&lrzs[256 + jl + hi4]);
        bf16x8 kaf = *reinterpret_cast<const bf16x8*>(&Ks[(jl + lo16) * KROW + hi * 8]);
        bf16x4 va0 = *reinterpret_cast<const bf16x4*>(&Vs[lo16 * VROW + jl + hi4]);
        bf16x4 va1 = *reinterpret_cast<const bf16x4*>(&Vs[(lo16 + 16) * VROW + jl + hi4]);
        #pragma unroll
        for (int f = 0; f < 4; ++f) {
            f32x4 s = __builtin_amdgcn_mfma_f32_16x16x32_bf16(kaf, qb[f], lz4, 0, 0, 0);
            bf16x4 e;
            #pragma unroll
            for (int r = 0; r < 4; ++r)
                e[r] = f2bf(__builtin_amdgcn_exp2f(s[r]));
            acc0[f] = __builtin_amdgcn_mfma_f32_16x16x16bf16_1k(va0, e, acc0[f], 0, 0, 0);
            acc1[f] = __builtin_amdgcn_mfma_f32_16x16x16bf16_1k(va1, e, acc1[f], 0, 0, 0);
        }
    }
    int icol = i0 + lo16;
    // Value conversion (__float2bfloat16), NOT f2bf bit-pattern (R2 lesson).
    #pragma unroll
    for (int f = 0; f < 4; ++f) {
        #pragma unroll
        for (int r = 0; r < 4; ++r) {
            oTp[(size_t)(jc * DH + hi4 + r)      * N_TOK + icol + f * 16] =
                __float2bfloat16(acc0[f][r]);
            oTp[(size_t)(jc * DH + 16 + hi4 + r) * N_TOK + icol + f * 16] =
                __float2bfloat16(acc1[f][r]);
        }
    }
}

// ---------------------------------------------------------------------------
// K4: reduce bf16 oT partials (16 chunks) then y = w4 @ o + b4 + x.
// Block = 32 tokens; 256 blocks (R6-proven shape).
// ---------------------------------------------------------------------------
__global__ __launch_bounds__(256) void k_fin(
        const __hip_bfloat16* __restrict__ oTp, const float* __restrict__ w4,
        const float* __restrict__ b4, const float* __restrict__ x,
        float* __restrict__ y) {
    __shared__ float w4s[64][32];
    __shared__ float tile[32][36];
    int t = threadIdx.x;
    {   // stage w4 (2048 f32)
        const float4* w4v = reinterpret_cast<const float4*>(w4);
        float4* dst = reinterpret_cast<float4*>(&w4s[0][0]);
        dst[t * 2]     = w4v[t * 2];
        dst[t * 2 + 1] = w4v[t * 2 + 1];
    }
    int n0 = blockIdx.x * 32;
    int d = t >> 3, seg = t & 7;
    float s[4];
    #pragma unroll
    for (int k = 0; k < 4; ++k) s[k] = 0.f;
    #pragma unroll 4
    for (int c = 0; c < NCH_O; ++c) {
        bf16x4 v = *reinterpret_cast<const bf16x4*>(
            oTp + ((size_t)c * DH + d) * N_TOK + n0 + seg * 4);
        #pragma unroll
        for (int k = 0; k < 4; ++k) s[k] += bf2f(v[k]);
    }
    #pragma unroll
    for (int k = 0; k < 4; ++k) tile[d][seg * 4 + k] = s[k];
    __syncthreads();
    int n_l = t & 31, cgr = t >> 5;
    int n = n0 + n_l, b = n >> 12, hw = n & 4095;
    #pragma unroll
    for (int ci = 0; ci < 8; ++ci) {
        int c = cgr * 8 + ci;
        float acc = b4[c];
        #pragma unroll
        for (int dd = 0; dd < 32; ++dd)
            acc = fmaf(w4s[c][dd], tile[dd][n_l], acc);
        int idx = b * (CCH * HWSZ) + c * HWSZ + hw;
        y[idx] = acc + x[idx];
    }
}

extern "C" void kernel_launch(void* const* d_in, const int* in_sizes, int n_in,
                              void* d_out, int out_size, void* d_ws, size_t ws_size,
                              hipStream_t stream) {
    const float* x  = (const float*)d_in[0];
    const float* w1 = (const float*)d_in[1];
    const float* b1 = (const float*)d_in[2];
    const float* w2 = (const float*)d_in[3];
    const float* b2 = (const float*)d_in[4];
    const float* w3 = (const float*)d_in[5];
    const float* b3 = (const float*)d_in[6];
    const float* w4 = (const float*)d_in[7];
    const float* b4 = (const float*)d_in[8];
    float* y = (float*)d_out;

    char* ws = (char*)d_ws;
    const size_t KB = 1024;
    __hip_bfloat16* Qb  = (__hip_bfloat16*)(ws);                  // 512 KB
    __hip_bfloat16* Kb  = (__hip_bfloat16*)(ws + 512 * KB);       // 512 KB
    __hip_bfloat16* VTb = (__hip_bfloat16*)(ws + 1024 * KB);      // 512 KB
    float*          Zp  = (float*)(ws + 1536 * KB);               // 1 MB (32 x 8192 f32)
    __hip_bfloat16* oTp = (__hip_bfloat16*)(ws + 2560 * KB);      // 8 MB (16 x 512KB)

    hipLaunchKernelGGL(k_qkv, dim3(N_TOK / 8), dim3(256), 0, stream,
                       x, w1, b1, w2, b2, w3, b3, Qb, Kb, VTb);
    hipLaunchKernelGGL(k_z,   dim3(1024), dim3(256), 0, stream, Qb, Kb, Zp);
    hipLaunchKernelGGL(k_af,  dim3(512),  dim3(256), 0, stream,
                       Qb, Kb, VTb, Zp, oTp);
    hipLaunchKernelGGL(k_fin, dim3(N_TOK / 32), dim3(256), 0, stream,
                       oTp, w4, b4, x, y);
}

// Round 20
// 54.646 us; speedup vs baseline: 1.0210x; 1.0210x over previous
//
#include <hip/hip_runtime.h>
#include <hip/hip_bf16.h>

// ===== R17 RESTORATION — session-best verified configuration (54.8 us) =====
// R18 (af occupancy x2: 55.6) and R19 (T14 async-stage: 55.8) both measured
// worse; af is VALU-throughput-bound on its exp2 chain, so neither extra
// waves nor load-latency hiding helps. This is R17's source verbatim.

// Problem constants: B=2, C=64, H=64, W=64 -> N=8192 tokens, DH=32.
#define N_TOK   8192
#define DH      32
#define CCH     64
#define HWSZ    4096
#define LOG2E   1.4426950408889634f
#define NCH_Z   32     // i-chunks in pass A (ilen = 256)
#define NCH_O   16     // j-chunks in pass B (jlen = 512, two staged halves)
#define KROW    40     // padded LDS row stride (shorts): 80B -> b128 conflict-free
#define VROW    264    // padded VT row stride (shorts) — R13-proven

typedef __attribute__((ext_vector_type(8))) short  bf16x8;
typedef __attribute__((ext_vector_type(4))) short  bf16x4;
typedef __attribute__((ext_vector_type(4))) float  f32x4;

// Bit-pattern f32 -> bf16 short (MFMA operand vectors / LDS shorts ONLY —
// never assign the result to a __hip_bfloat16: that would value-convert).
static __device__ __forceinline__ short f2bf(float f) {
    __hip_bfloat16 h = __float2bfloat16(f);
    return __builtin_bit_cast(short, h);
}
static __device__ __forceinline__ float bf2f(short s) {
    unsigned u = ((unsigned)(unsigned short)s) << 16;
    return __builtin_bit_cast(float, u);
}

// A/B fragment for mfma_f32_16x16x32_bf16 from row-major [rows][32] bf16 in
// GLOBAL memory: lane l supplies row row0+(l&15), k = 8*(l>>4)..+8.
static __device__ __forceinline__ bf16x8 load_frag8(const __hip_bfloat16* __restrict__ base,
                                                    int row0, int l) {
    const __hip_bfloat16* p = base + (size_t)(row0 + (l & 15)) * DH + ((l >> 4) << 3);
    return *reinterpret_cast<const bf16x8*>(p);
}

// ---------------------------------------------------------------------------
// K1: q/k/v projections (1024 blocks, 8 tokens each — measured ~5.7us true).
// Qb pre-scaled by log2e; VTb transposed via LDS.
// ---------------------------------------------------------------------------
__global__ __launch_bounds__(256) void k_qkv(
        const float* __restrict__ x,
        const float* __restrict__ w1, const float* __restrict__ b1,
        const float* __restrict__ w2, const float* __restrict__ b2,
        const float* __restrict__ w3, const float* __restrict__ b3,
        __hip_bfloat16* __restrict__ Qb, __hip_bfloat16* __restrict__ Kb,
        __hip_bfloat16* __restrict__ VTb) {
    __shared__ float4 w1s[16][32];
    __shared__ float4 w2s[16][32];
    __shared__ float4 w3s[16][32];
    __shared__ short  vt[32][8];
    int t = threadIdx.x;
    for (int i = t; i < 512; i += 256) {
        int cg = i >> 5, d = i & 31;
        w1s[cg][d] = *reinterpret_cast<const float4*>(w1 + d * CCH + cg * 4);
        w2s[cg][d] = *reinterpret_cast<const float4*>(w2 + d * CCH + cg * 4);
        w3s[cg][d] = *reinterpret_cast<const float4*>(w3 + d * CCH + cg * 4);
    }
    __syncthreads();
    int d = t & 31, nr = t >> 5;
    int n0 = blockIdx.x * 8;
    int n = n0 + nr;
    int b = n >> 12, hw = n & 4095;
    const float* xp = x + (size_t)b * (CCH * HWSZ) + hw;
    float aq = b1[d], ak = b2[d], av = b3[d];
    #pragma unroll
    for (int cg = 0; cg < 16; ++cg) {
        float x0 = xp[(cg * 4 + 0) * HWSZ];
        float x1 = xp[(cg * 4 + 1) * HWSZ];
        float x2 = xp[(cg * 4 + 2) * HWSZ];
        float x3 = xp[(cg * 4 + 3) * HWSZ];
        float4 a = w1s[cg][d];
        aq = fmaf(a.x, x0, aq); aq = fmaf(a.y, x1, aq);
        aq = fmaf(a.z, x2, aq); aq = fmaf(a.w, x3, aq);
        float4 bb = w2s[cg][d];
        ak = fmaf(bb.x, x0, ak); ak = fmaf(bb.y, x1, ak);
        ak = fmaf(bb.z, x2, ak); ak = fmaf(bb.w, x3, ak);
        float4 cc = w3s[cg][d];
        av = fmaf(cc.x, x0, av); av = fmaf(cc.y, x1, av);
        av = fmaf(cc.z, x2, av); av = fmaf(cc.w, x3, av);
    }
    Qb[(size_t)n * DH + d] = __float2bfloat16(aq * LOG2E);
    Kb[(size_t)n * DH + d] = __float2bfloat16(ak);
    vt[d][nr] = f2bf(av);
    __syncthreads();
    if (t < 32) {
        bf16x8 row = *reinterpret_cast<const bf16x8*>(&vt[t][0]);
        *reinterpret_cast<bf16x8*>(VTb + (size_t)t * N_TOK + n0) = row;
    }
}

// ---------------------------------------------------------------------------
// K2 (pass A): Zp[ic][j] = sum_{i in chunk ic} exp2(q~_i . k_j).
// 256-thread block, 4 waves sharing a staged 256-row Q chunk ([256][40]
// padded -> conflict-free b128). Wave w owns j-tile jtg*4+w.
// Grid = 32 ic x 32 jtg = 1024 blocks.
// ---------------------------------------------------------------------------
__global__ __launch_bounds__(256, 4) void k_z(
        const __hip_bfloat16* __restrict__ Qb, const __hip_bfloat16* __restrict__ Kb,
        float* __restrict__ Zp) {
    __shared__ short Qs[256 * KROW];   // 20 KB
    int t = threadIdx.x;
    int ic  = blockIdx.x & 31;           // i-chunk 0..31
    int jtg = blockIdx.x >> 5;           // 0..31
    int i0c = ic * 256;
    #pragma unroll
    for (int p = 0; p < 4; ++p) {
        int row = p * 64 + (t >> 2), seg = t & 3;
        bf16x8 v = *reinterpret_cast<const bf16x8*>(
            Qb + (size_t)(i0c + row) * DH + seg * 8);
        *reinterpret_cast<bf16x8*>(&Qs[row * KROW + seg * 8]) = v;
    }
    __syncthreads();
    int l = t & 63, w = t >> 6;
    int lo16 = l & 15, hi = l >> 4;
    int j0 = (jtg * 4 + w) * 64;
    bf16x8 ka[4];
    #pragma unroll
    for (int f = 0; f < 4; ++f) ka[f] = load_frag8(Kb, j0 + f * 16, l);
    float zac[16];
    #pragma unroll
    for (int k = 0; k < 16; ++k) zac[k] = 0.f;
    const f32x4 z4 = {0.f, 0.f, 0.f, 0.f};
    #pragma unroll 2
    for (int il = 0; il < 256; il += 16) {
        bf16x8 qf = *reinterpret_cast<const bf16x8*>(&Qs[(il + lo16) * KROW + hi * 8]);
        #pragma unroll
        for (int f = 0; f < 4; ++f) {
            f32x4 s = __builtin_amdgcn_mfma_f32_16x16x32_bf16(ka[f], qf, z4, 0, 0, 0);
            #pragma unroll
            for (int r = 0; r < 4; ++r)
                zac[f * 4 + r] += __builtin_amdgcn_exp2f(s[r]);
        }
    }
    #pragma unroll
    for (int k = 0; k < 16; ++k) {
        float z = zac[k];
        z += __shfl_xor(z, 1); z += __shfl_xor(z, 2);
        z += __shfl_xor(z, 4); z += __shfl_xor(z, 8);
        zac[k] = z;
    }
    if ((l & 15) == 0) {
        int jr = (l >> 4) * 4;
        #pragma unroll
        for (int f = 0; f < 4; ++f)
            #pragma unroll
            for (int r = 0; r < 4; ++r)
                Zp[(size_t)ic * N_TOK + j0 + f * 16 + jr + r] = zac[f * 4 + r];
    }
}

// ---------------------------------------------------------------------------
// K3 (pass B): block = one 512-col j-chunk processed as TWO staged 256-col
// halves (same 37.5KB LDS buffers re-staged). Preamble computes
// lrz_j = -log2(Z_j) for all 512 cols; the QK MFMA takes lrz as its C
// operand, so s comes out pre-shifted and e = exp2(s) directly — no
// per-element rz multiply. Wave w owns 64 rows (4 Q frags).
// Grid = 32 itg x 16 jc = 512 blocks.
// ---------------------------------------------------------------------------
__global__ __launch_bounds__(256, 4) void k_af(
        const __hip_bfloat16* __restrict__ Qb, const __hip_bfloat16* __restrict__ Kb,
        const __hip_bfloat16* __restrict__ VTb, const float* __restrict__ Zp,
        __hip_bfloat16* __restrict__ oTp) {
    __shared__ short Ks[256 * KROW];   // 20 KB
    __shared__ short Vs[32 * VROW];    // 16.5 KB
    __shared__ float lrzs[512];        // 2 KB
    int t = threadIdx.x;
    int jc  = blockIdx.x & 15;           // j-chunk (512 cols)
    int itg = blockIdx.x >> 4;           // 0..31
    int j0c = jc * 512;
    {   // lrz = -log2(Z) for 512 cols (fixed order -> deterministic)
        float z0 = 0.f, z1 = 0.f;
        #pragma unroll 8
        for (int c = 0; c < NCH_Z; ++c) {
            z0 += Zp[(size_t)c * N_TOK + j0c + t];
            z1 += Zp[(size_t)c * N_TOK + j0c + 256 + t];
        }
        lrzs[t]       = -__builtin_amdgcn_logf(z0);
        lrzs[t + 256] = -__builtin_amdgcn_logf(z1);
    }
    int l = t & 63, w = t >> 6;
    int lo16 = l & 15, hi = l >> 4, hi4 = hi << 2;
    int it = itg * 4 + w;                // 0..127
    int i0 = it * 64;
    bf16x8 qb[4];
    #pragma unroll
    for (int f = 0; f < 4; ++f) qb[f] = load_frag8(Qb, i0 + f * 16, l);
    f32x4 acc0[4], acc1[4];
    #pragma unroll
    for (int f = 0; f < 4; ++f) { acc0[f] = {0.f,0.f,0.f,0.f}; acc1[f] = {0.f,0.f,0.f,0.f}; }
    #pragma unroll
    for (int h = 0; h < 2; ++h) {
        int jb = j0c + h * 256;
        if (h) __syncthreads();          // protect re-staging of Ks/Vs
        // stage K half-tile: 16 KB (4 passes of 256 x 16B) — R13 pattern
        #pragma unroll
        for (int p = 0; p < 4; ++p) {
            int row = p * 64 + (t >> 2), seg = t & 3;
            bf16x8 v = *reinterpret_cast<const bf16x8*>(
                Kb + (size_t)(jb + row) * DH + seg * 8);
            *reinterpret_cast<bf16x8*>(&Ks[row * KROW + seg * 8]) = v;
        }
        // stage VT half-tile: 32 rows x 256 shorts — R13 pattern
        {
            int d = t >> 3, part = t & 7;
            const __hip_bfloat16* src = VTb + (size_t)d * N_TOK + jb + part * 32;
            #pragma unroll
            for (int q = 0; q < 4; ++q) {
                bf16x8 v = *reinterpret_cast<const bf16x8*>(src + q * 8);
                *reinterpret_cast<bf16x8*>(&Vs[d * VROW + part * 32 + q * 8]) = v;
            }
        }
        __syncthreads();
        #pragma unroll 2
        for (int jl = 0; jl < 256; jl += 16) {
            f32x4 lz4 = *reinterpret_cast<const f32x4*>(&lrzs[h * 256 + jl + hi4]);
            bf16x8 kaf = *reinterpret_cast<const bf16x8*>(&Ks[(jl + lo16) * KROW + hi * 8]);
            bf16x4 va0 = *reinterpret_cast<const bf16x4*>(&Vs[lo16 * VROW + jl + hi4]);
            bf16x4 va1 = *reinterpret_cast<const bf16x4*>(&Vs[(lo16 + 16) * VROW + jl + hi4]);
            #pragma unroll
            for (int f = 0; f < 4; ++f) {
                // C = lrz -> s arrives pre-shifted; e = exp2(s) includes 1/Z.
                f32x4 s = __builtin_amdgcn_mfma_f32_16x16x32_bf16(kaf, qb[f], lz4, 0, 0, 0);
                bf16x4 e;
                #pragma unroll
                for (int r = 0; r < 4; ++r)
                    e[r] = f2bf(__builtin_amdgcn_exp2f(s[r]));
                acc0[f] = __builtin_amdgcn_mfma_f32_16x16x16bf16_1k(va0, e, acc0[f], 0, 0, 0);
                acc1[f] = __builtin_amdgcn_mfma_f32_16x16x16bf16_1k(va1, e, acc1[f], 0, 0, 0);
            }
        }
    }
    int icol = i0 + lo16;
    // Value conversion (__float2bfloat16), NOT f2bf bit-pattern (R2 lesson).
    #pragma unroll
    for (int f = 0; f < 4; ++f) {
        #pragma unroll
        for (int r = 0; r < 4; ++r) {
            oTp[(size_t)(jc * DH + hi4 + r)      * N_TOK + icol + f * 16] =
                __float2bfloat16(acc0[f][r]);
            oTp[(size_t)(jc * DH + 16 + hi4 + r) * N_TOK + icol + f * 16] =
                __float2bfloat16(acc1[f][r]);
        }
    }
}

// ---------------------------------------------------------------------------
// K4: reduce bf16 oT partials (16 chunks) then y = w4 @ o + b4 + x.
// Block = 32 tokens; 256 blocks (R6-proven shape).
// ---------------------------------------------------------------------------
__global__ __launch_bounds__(256) void k_fin(
        const __hip_bfloat16* __restrict__ oTp, const float* __restrict__ w4,
        const float* __restrict__ b4, const float* __restrict__ x,
        float* __restrict__ y) {
    __shared__ float w4s[64][32];
    __shared__ float tile[32][36];
    int t = threadIdx.x;
    {   // stage w4 (2048 f32)
        const float4* w4v = reinterpret_cast<const float4*>(w4);
        float4* dst = reinterpret_cast<float4*>(&w4s[0][0]);
        dst[t * 2]     = w4v[t * 2];
        dst[t * 2 + 1] = w4v[t * 2 + 1];
    }
    int n0 = blockIdx.x * 32;
    int d = t >> 3, seg = t & 7;
    float s[4];
    #pragma unroll
    for (int k = 0; k < 4; ++k) s[k] = 0.f;
    #pragma unroll 4
    for (int c = 0; c < NCH_O; ++c) {
        bf16x4 v = *reinterpret_cast<const bf16x4*>(
            oTp + ((size_t)c * DH + d) * N_TOK + n0 + seg * 4);
        #pragma unroll
        for (int k = 0; k < 4; ++k) s[k] += bf2f(v[k]);
    }
    #pragma unroll
    for (int k = 0; k < 4; ++k) tile[d][seg * 4 + k] = s[k];
    __syncthreads();
    int n_l = t & 31, cgr = t >> 5;
    int n = n0 + n_l, b = n >> 12, hw = n & 4095;
    #pragma unroll
    for (int ci = 0; ci < 8; ++ci) {
        int c = cgr * 8 + ci;
        float acc = b4[c];
        #pragma unroll
        for (int dd = 0; dd < 32; ++dd)
            acc = fmaf(w4s[c][dd], tile[dd][n_l], acc);
        int idx = b * (CCH * HWSZ) + c * HWSZ + hw;
        y[idx] = acc + x[idx];
    }
}

extern "C" void kernel_launch(void* const* d_in, const int* in_sizes, int n_in,
                              void* d_out, int out_size, void* d_ws, size_t ws_size,
                              hipStream_t stream) {
    const float* x  = (const float*)d_in[0];
    const float* w1 = (const float*)d_in[1];
    const float* b1 = (const float*)d_in[2];
    const float* w2 = (const float*)d_in[3];
    const float* b2 = (const float*)d_in[4];
    const float* w3 = (const float*)d_in[5];
    const float* b3 = (const float*)d_in[6];
    const float* w4 = (const float*)d_in[7];
    const float* b4 = (const float*)d_in[8];
    float* y = (float*)d_out;

    char* ws = (char*)d_ws;
    const size_t KB = 1024;
    __hip_bfloat16* Qb  = (__hip_bfloat16*)(ws);                  // 512 KB
    __hip_bfloat16* Kb  = (__hip_bfloat16*)(ws + 512 * KB);       // 512 KB
    __hip_bfloat16* VTb = (__hip_bfloat16*)(ws + 1024 * KB);      // 512 KB
    float*          Zp  = (float*)(ws + 1536 * KB);               // 1 MB (32 x 8192 f32)
    __hip_bfloat16* oTp = (__hip_bfloat16*)(ws + 2560 * KB);      // 8 MB (16 x 512KB)

    hipLaunchKernelGGL(k_qkv, dim3(N_TOK / 8), dim3(256), 0, stream,
                       x, w1, b1, w2, b2, w3, b3, Qb, Kb, VTb);
    hipLaunchKernelGGL(k_z,   dim3(1024), dim3(256), 0, stream, Qb, Kb, Zp);
    hipLaunchKernelGGL(k_af,  dim3(512),  dim3(256), 0, stream,
                       Qb, Kb, VTb, Zp, oTp);
    hipLaunchKernelGGL(k_fin, dim3(N_TOK / 32), dim3(256), 0, stream,
                       oTp, w4, b4, x, y);
}